// Round 6
// baseline (673.884 us; speedup 1.0000x reference)
//
#include <hip/hip_runtime.h>

namespace {

constexpr int kS = 1024;
constexpr int kD = 64;
constexpr int kH = 128;

typedef __attribute__((ext_vector_type(2))) _Float16 half2v;
typedef __attribute__((ext_vector_type(4))) float f32x4;
typedef __attribute__((ext_vector_type(8))) _Float16 half8;

__device__ __forceinline__ float fdot2(unsigned w, unsigned h, float acc) {
#if __has_builtin(__builtin_amdgcn_fdot2)
  return __builtin_amdgcn_fdot2(__builtin_bit_cast(half2v, w),
                                __builtin_bit_cast(half2v, h), acc, false);
#else
  float d;
  asm("v_dot2_f32_f16 %0, %1, %2, %3" : "=v"(d) : "v"(w), "v"(h), "v"(acc));
  return d;
#endif
}

// RNE f16 pack (cvt_pkrtz is RTZ -> systematic shrink bias over 1024 steps)
__device__ __forceinline__ unsigned pk16(float a, float b) {
  half2v h;
  h.x = (_Float16)a;
  h.y = (_Float16)b;
  return __builtin_bit_cast(unsigned, h);
}

__device__ __forceinline__ float fast_tanh(float x) {
#if __has_builtin(__builtin_amdgcn_fmed3f)
  x = __builtin_amdgcn_fmed3f(x, -15.f, 15.f);  // single-instr clamp
#else
  x = fminf(fmaxf(x, -15.f), 15.f);
#endif
  float e = __expf(2.f * x);
  return (e - 1.f) * __builtin_amdgcn_rcpf(e + 1.f);
}

// async global->LDS: 8 x 16B/lane = one 8 KB xp chunk (no VGPR round-trip)
__device__ __forceinline__ void stage_chunk(const char* g, unsigned* lds, int L) {
#pragma unroll
  for (int k = 0; k < 8; ++k) {
    __builtin_amdgcn_global_load_lds(
        (const __attribute__((address_space(1))) void*)(g + k * 1024 + L * 16),
        (__attribute__((address_space(3))) void*)(lds + k * 256), 16, 0, 0);
  }
}

// xp (f16) layout per (dir,b) slab of kS*kH elems, chunk-transposed:
//   idx = (t>>5)*(32*kH) + (t&31)*kH + j     (dir=1 pre-time-reversed)
// -> one 32-step chunk = 8 KB contiguous, DMA-stageable.

// =====================  Phase A: x-projection via f16 MFMA  =====================
// (unchanged: 84 us, correct)
__global__ __launch_bounds__(256, 2) void xproj_kernel(
    const float* __restrict__ inputs,
    const float* __restrict__ Wih_fw, const float* __restrict__ bih_fw,
    const float* __restrict__ bhh_fw,
    const float* __restrict__ Wih_bw, const float* __restrict__ bih_bw,
    const float* __restrict__ bhh_bw,
    _Float16* __restrict__ xp) {
  __shared__ _Float16 Wl[256 * 80];
  __shared__ _Float16 xl[128 * 80];
  __shared__ float biasl[256];

  const int tid = threadIdx.x;
  const int b = blockIdx.x;
  const int w = tid >> 6;
  const int lane = tid & 63;
  const int n16 = lane & 15;
  const int q = lane >> 4;

  {
    const int jd = tid;
    const float* src = (jd < kH) ? (Wih_fw + jd * kD) : (Wih_bw + (jd - kH) * kD);
    const float4* s4 = (const float4*)src;
#pragma unroll
    for (int k = 0; k < 8; ++k) {
      float4 a = s4[2 * k], c = s4[2 * k + 1];
      half8 h;
      h[0] = (_Float16)a.x; h[1] = (_Float16)a.y; h[2] = (_Float16)a.z; h[3] = (_Float16)a.w;
      h[4] = (_Float16)c.x; h[5] = (_Float16)c.y; h[6] = (_Float16)c.z; h[7] = (_Float16)c.w;
      *(half8*)&Wl[jd * 80 + k * 8] = h;
    }
    biasl[jd] = (jd < kH) ? (bih_fw[jd] + bhh_fw[jd])
                          : (bih_bw[jd - kH] + bhh_bw[jd - kH]);
  }

  for (int ch = 0; ch < 8; ++ch) {
    __syncthreads();
    {
      const int tl = tid >> 1, hf = tid & 1;
      const float4* s4 = (const float4*)(inputs +
          ((size_t)b * kS + ch * 128 + tl) * kD + hf * 32);
#pragma unroll
      for (int k = 0; k < 4; ++k) {
        float4 a = s4[2 * k], c = s4[2 * k + 1];
        half8 h;
        h[0] = (_Float16)a.x; h[1] = (_Float16)a.y; h[2] = (_Float16)a.z; h[3] = (_Float16)a.w;
        h[4] = (_Float16)c.x; h[5] = (_Float16)c.y; h[6] = (_Float16)c.z; h[7] = (_Float16)c.w;
        *(half8*)&xl[tl * 80 + hf * 32 + k * 8] = h;
      }
    }
    __syncthreads();

    half8 bf0[4], bf1[4];
    float bs[4];
#pragma unroll
    for (int nn = 0; nn < 4; ++nn) {
      const int jd = (w * 4 + nn) * 16 + n16;
      bf0[nn] = *(const half8*)&Wl[jd * 80 + q * 8];
      bf1[nn] = *(const half8*)&Wl[jd * 80 + q * 8 + 32];
      bs[nn] = biasl[jd];
    }

#pragma unroll 2
    for (int m = 0; m < 8; ++m) {
      const int trow = m * 16 + n16;
      const half8 a0 = *(const half8*)&xl[trow * 80 + q * 8];
      const half8 a1 = *(const half8*)&xl[trow * 80 + q * 8 + 32];
#pragma unroll
      for (int nn = 0; nn < 4; ++nn) {
        f32x4 acc = {0.f, 0.f, 0.f, 0.f};
        acc = __builtin_amdgcn_mfma_f32_16x16x32_f16(a0, bf0[nn], acc, 0, 0, 0);
        acc = __builtin_amdgcn_mfma_f32_16x16x32_f16(a1, bf1[nn], acc, 0, 0, 0);
        const int jd = (w * 4 + nn) * 16 + n16;
        const int dir = jd >> 7, j = jd & 127;
        const size_t slab = (size_t)(dir * 256 + b) * (kS * kH);
#pragma unroll
        for (int r = 0; r < 4; ++r) {
          const int t = ch * 128 + m * 16 + q * 4 + r;
          const int tt = dir ? (kS - 1 - t) : t;
          xp[slab + (size_t)(tt >> 5) * (32 * kH) + (tt & 31) * kH + j] =
              (_Float16)(acc[r] + bs[nn]);
        }
      }
    }
  }
}

// =====================  Phase B: MFMA recurrence, 2 chains/wave  ================
// 256 blocks x 64 threads (ONE wave): dir = blockIdx>>7, chains (2bp, 2bp+1).
// Per step: h_new = tanh(W*h + x) via 32x mfma_f32_16x16x32_f16 (8 M-tiles x
// 4 K-tiles). B columns alternate the 2 chains (col n -> chain n&1), so one
// MFMA sweep serves both. Fragment layouts identical to the verified xproj use:
//   A: row=lane&15, k=(lane>>4)*8+j;  B: col=lane&15, k=(lane>>4)*8+j;
//   C: col=lane&15, row=(lane>>4)*4+r.
// Each lane then owns (chain=L&1, q=L>>4, tile=(L>>1)&7): static cndmask tree
// selects its C quad (no runtime reg indexing -> no scratch), adds x, tanh x4,
// packs and writes one b64 into the jrn ring; next step's B-frags are 4 uniform
// ds_read_b128 from jrn[prev]. Single wave => lockstep, no barriers.
__global__ __launch_bounds__(64, 1) void birnn_step_kernel(
    const _Float16* __restrict__ xp,
    const float* __restrict__ Whh_fw, const float* __restrict__ Whh_bw,
    const float* __restrict__ fcW, const float* __restrict__ fcb,
    float* __restrict__ out) {
  const int dir = blockIdx.x >> 7;
  const int bp = blockIdx.x & 127;
  const int b0 = 2 * bp, b1 = 2 * bp + 1;
  const int L = threadIdx.x;
  const int n16 = L & 15;
  const int q = L >> 4;
  const int ch = L & 1;
  const int myt = (L >> 1) & 7;

  // jrn[ch][s][68]: h ring + fc journal. 68-dw rows: b128-aligned, s-stride
  // = 68 = 4 mod 32 dwords (fc-drain conflicts capped at 4-way).
  __shared__ unsigned jrn[2 * 32 * 68];
  __shared__ unsigned xbuf[2][2][2048];  // [chain][dbuf][8 KB chunk]
  __shared__ unsigned fcwl[64];          // fc weights, packed f16 pairs
  __shared__ float outbuf[2][kS];

  const float* __restrict__ Whh = dir ? Whh_bw : Whh_fw;

  // ---- A-fragments: W[16*tm + n16][32*tk + 8q .. +7] as half8 (128 VGPRs) ----
  half8 Afr[8][4];
#pragma unroll
  for (int tm = 0; tm < 8; ++tm) {
#pragma unroll
    for (int tk = 0; tk < 4; ++tk) {
      const float* src = Whh + (size_t)(16 * tm + n16) * kH + 32 * tk + 8 * q;
      const float4 a = *(const float4*)src;
      const float4 c = *(const float4*)(src + 4);
      half8 h;
      h[0] = (_Float16)a.x; h[1] = (_Float16)a.y; h[2] = (_Float16)a.z; h[3] = (_Float16)a.w;
      h[4] = (_Float16)c.x; h[5] = (_Float16)c.y; h[6] = (_Float16)c.z; h[7] = (_Float16)c.w;
      Afr[tm][tk] = h;
    }
  }
  fcwl[L] = pk16(fcW[dir * kH + 2 * L], fcW[dir * kH + 2 * L + 1]);
  jrn[31 * 68 + L] = 0;         // h_{-1} = 0, chain 0
  jrn[2176 + 31 * 68 + L] = 0;  // h_{-1} = 0, chain 1

  const f32x4 zeroq = {0.f, 0.f, 0.f, 0.f};

  // ---- prime xp chunks 0,1 for both chains ----
  const char* slabA = (const char*)(xp + (size_t)(dir * 256 + b0) * (kS * kH));
  const char* slabB = (const char*)(xp + (size_t)(dir * 256 + b1) * (kS * kH));
  stage_chunk(slabA, &xbuf[0][0][0], L);
  stage_chunk(slabB, &xbuf[1][0][0], L);
  stage_chunk(slabA + 8192, &xbuf[0][1][0], L);
  stage_chunk(slabB + 8192, &xbuf[1][1][0], L);
  asm volatile("s_waitcnt vmcnt(16)" ::: "memory");  // chunk 0 (A+B) resident

  const int jbase = ch * 2176;        // chain base in jrn (dwords)
  const int wr_off = 8 * myt + 2 * q; // this lane's h dword pair within a row

  for (int c = 0; c < 32; ++c) {
    const unsigned* xs = &xbuf[0][0][0] + ch * 4096 + (c & 1) * 2048;

    for (int s = 0; s < 32; ++s) {
      const int prev = (s + 31) & 31;
      const unsigned* brow = &jrn[jbase + prev * 68 + 4 * q];
      const uint4 B0 = *(const uint4*)(brow);
      const uint4 B1 = *(const uint4*)(brow + 16);
      const uint4 B2 = *(const uint4*)(brow + 32);
      const uint4 B3 = *(const uint4*)(brow + 48);
      const uint2 xv = *(const uint2*)(xs + s * 64 + wr_off);

      const half8 b0f = __builtin_bit_cast(half8, B0);
      const half8 b1f = __builtin_bit_cast(half8, B1);
      const half8 b2f = __builtin_bit_cast(half8, B2);
      const half8 b3f = __builtin_bit_cast(half8, B3);

      f32x4 Cacc[8];
#pragma unroll
      for (int t = 0; t < 8; ++t)
        Cacc[t] = __builtin_amdgcn_mfma_f32_16x16x32_f16(Afr[t][0], b0f, zeroq, 0, 0, 0);
#pragma unroll
      for (int t = 0; t < 8; ++t)
        Cacc[t] = __builtin_amdgcn_mfma_f32_16x16x32_f16(Afr[t][1], b1f, Cacc[t], 0, 0, 0);
#pragma unroll
      for (int t = 0; t < 8; ++t)
        Cacc[t] = __builtin_amdgcn_mfma_f32_16x16x32_f16(Afr[t][2], b2f, Cacc[t], 0, 0, 0);
#pragma unroll
      for (int t = 0; t < 8; ++t)
        Cacc[t] = __builtin_amdgcn_mfma_f32_16x16x32_f16(Afr[t][3], b3f, Cacc[t], 0, 0, 0);

      // static 8->1 select of this lane's tile (myt) — 28 cndmask, no scratch
      const f32x4 t01 = (myt & 1) ? Cacc[1] : Cacc[0];
      const f32x4 t23 = (myt & 1) ? Cacc[3] : Cacc[2];
      const f32x4 t45 = (myt & 1) ? Cacc[5] : Cacc[4];
      const f32x4 t67 = (myt & 1) ? Cacc[7] : Cacc[6];
      const f32x4 u0 = (myt & 2) ? t23 : t01;
      const f32x4 u1 = (myt & 2) ? t67 : t45;
      const f32x4 sel = (myt & 4) ? u1 : u0;

      const half2v x01 = __builtin_bit_cast(half2v, xv.x);
      const half2v x23 = __builtin_bit_cast(half2v, xv.y);
      const float h0 = fast_tanh(sel[0] + (float)x01.x);
      const float h1 = fast_tanh(sel[1] + (float)x01.y);
      const float h2 = fast_tanh(sel[2] + (float)x23.x);
      const float h3 = fast_tanh(sel[3] + (float)x23.y);

      uint2 hw;
      hw.x = pk16(h0, h1);
      hw.y = pk16(h2, h3);
      *(uint2*)&jrn[jbase + s * 68 + wr_off] = hw;
    }

    // ---- fc drain of chunk c: lane L -> (step L>>1, chain L&1), full 128-dot
    {
      const int ds = L >> 1, dch = L & 1;
      const unsigned* rp = &jrn[dch * 2176 + ds * 68];
      float acc = 0.f;
#pragma unroll
      for (int k = 0; k < 16; ++k) {
        const uint4 hv = *(const uint4*)(rp + 4 * k);
        const uint4 fw = *(const uint4*)&fcwl[4 * k];
        acc = fdot2(fw.x, hv.x, acc);
        acc = fdot2(fw.y, hv.y, acc);
        acc = fdot2(fw.z, hv.z, acc);
        acc = fdot2(fw.w, hv.w, acc);
      }
      outbuf[dch][c * 32 + ds] = acc;
    }

    // ---- stage chunk c+2 (both chains) into freed buffers; gate chunk c+1 ----
    if (c < 30) {
      stage_chunk(slabA + (size_t)(c + 2) * 8192, &xbuf[0][c & 1][0], L);
      stage_chunk(slabB + (size_t)(c + 2) * 8192, &xbuf[1][c & 1][0], L);
      asm volatile("s_waitcnt vmcnt(16)" ::: "memory");
    } else if (c == 30) {
      asm volatile("s_waitcnt vmcnt(0)" ::: "memory");
    }
  }

  // ---- emit: one atomic pass per chain (fw adds fcb) ----
  const float fcb0 = (dir == 0) ? fcb[0] : 0.f;
#pragma unroll
  for (int k = 0; k < 16; ++k) {
    const int t = L + 64 * k;
    const int td = dir ? (kS - 1 - t) : t;
    atomicAdd(&out[(size_t)b0 * kS + td], outbuf[0][t] + fcb0);
    atomicAdd(&out[(size_t)b1 * kS + td], outbuf[1][t] + fcb0);
  }
}

}  // namespace

extern "C" void kernel_launch(void* const* d_in, const int* in_sizes, int n_in,
                              void* d_out, int out_size, void* d_ws, size_t ws_size,
                              hipStream_t stream) {
  (void)in_sizes; (void)n_in; (void)ws_size;
  const float* inputs = (const float*)d_in[0];
  const float* Wih_fw = (const float*)d_in[1];
  const float* Whh_fw = (const float*)d_in[2];
  const float* bih_fw = (const float*)d_in[3];
  const float* bhh_fw = (const float*)d_in[4];
  const float* Wih_bw = (const float*)d_in[5];
  const float* Whh_bw = (const float*)d_in[6];
  const float* bih_bw = (const float*)d_in[7];
  const float* bhh_bw = (const float*)d_in[8];
  const float* fc_W   = (const float*)d_in[9];
  const float* fc_b   = (const float*)d_in[10];
  float* out = (float*)d_out;
  _Float16* xpw = (_Float16*)d_ws;  // 2*256*1024*128 f16 = 128 MiB

  hipMemsetAsync(out, 0, (size_t)out_size * sizeof(float), stream);

  hipLaunchKernelGGL(xproj_kernel, dim3(256), dim3(256), 0, stream,
                     inputs, Wih_fw, bih_fw, bhh_fw, Wih_bw, bih_bw, bhh_bw, xpw);
  hipLaunchKernelGGL(birnn_step_kernel, dim3(256), dim3(64), 0, stream,
                     xpw, Whh_fw, Whh_bw, fc_W, fc_b, out);
}

// Round 7
// 567.582 us; speedup vs baseline: 1.1873x; 1.1873x over previous
//
#include <hip/hip_runtime.h>

namespace {

constexpr int kS = 1024;
constexpr int kD = 64;
constexpr int kH = 128;

typedef __attribute__((ext_vector_type(2))) _Float16 half2v;
typedef __attribute__((ext_vector_type(4))) float f32x4;
typedef __attribute__((ext_vector_type(8))) _Float16 half8;

__device__ __forceinline__ float fdot2(unsigned w, unsigned h, float acc) {
#if __has_builtin(__builtin_amdgcn_fdot2)
  return __builtin_amdgcn_fdot2(__builtin_bit_cast(half2v, w),
                                __builtin_bit_cast(half2v, h), acc, false);
#else
  float d;
  asm("v_dot2_f32_f16 %0, %1, %2, %3" : "=v"(d) : "v"(w), "v"(h), "v"(acc));
  return d;
#endif
}

// broadcast lane k's packed h-dword to all lanes, result in VGPR (no SGPR hop,
// no LDS memory round-trip). Uniform index -> pure broadcast, conflict-free.
__device__ __forceinline__ unsigned bcast(unsigned v, int k) {
  return (unsigned)__builtin_amdgcn_ds_bpermute(4 * k, (int)v);
}

// RNE f16 pack (cvt_pkrtz is RTZ -> systematic shrink bias over 1024 steps)
__device__ __forceinline__ unsigned pk16(float a, float b) {
  half2v h;
  h.x = (_Float16)a;
  h.y = (_Float16)b;
  return __builtin_bit_cast(unsigned, h);
}

__device__ __forceinline__ float fast_tanh(float x) {
#if __has_builtin(__builtin_amdgcn_fmed3f)
  x = __builtin_amdgcn_fmed3f(x, -15.f, 15.f);  // single-instr clamp
#else
  x = fminf(fmaxf(x, -15.f), 15.f);
#endif
  float e = __expf(2.f * x);
  return (e - 1.f) * __builtin_amdgcn_rcpf(e + 1.f);
}

#if __has_builtin(__builtin_amdgcn_mov_dpp)
__device__ __forceinline__ float lane_xor1(float v) {
  return __int_as_float(__builtin_amdgcn_mov_dpp(__float_as_int(v), 0xB1, 0xF, 0xF, true));
}
#else
__device__ __forceinline__ float lane_xor1(float v) {
  return __int_as_float(__builtin_amdgcn_ds_swizzle(__float_as_int(v), 0x041F));
}
#endif

// async global->LDS: 8 x 16B/lane = one 8 KB xp chunk (no VGPR round-trip)
__device__ __forceinline__ void stage_chunk(const char* g, unsigned* lds, int L) {
#pragma unroll
  for (int k = 0; k < 8; ++k) {
    __builtin_amdgcn_global_load_lds(
        (const __attribute__((address_space(1))) void*)(g + k * 1024 + L * 16),
        (__attribute__((address_space(3))) void*)(lds + k * 256), 16, 0, 0);
  }
}

// xp (f16) layout per (dir,b) slab of kS*kH elems, chunk-transposed:
//   idx = (t>>5)*(32*kH) + (t&31)*kH + j     (dir=1 pre-time-reversed)
// -> one 32-step chunk = 8 KB contiguous, DMA-stageable.

// =====================  Phase A: x-projection via f16 MFMA  =====================
// (unchanged: 84 us, correct)
__global__ __launch_bounds__(256, 2) void xproj_kernel(
    const float* __restrict__ inputs,
    const float* __restrict__ Wih_fw, const float* __restrict__ bih_fw,
    const float* __restrict__ bhh_fw,
    const float* __restrict__ Wih_bw, const float* __restrict__ bih_bw,
    const float* __restrict__ bhh_bw,
    _Float16* __restrict__ xp) {
  __shared__ _Float16 Wl[256 * 80];
  __shared__ _Float16 xl[128 * 80];
  __shared__ float biasl[256];

  const int tid = threadIdx.x;
  const int b = blockIdx.x;
  const int w = tid >> 6;
  const int lane = tid & 63;
  const int n16 = lane & 15;
  const int q = lane >> 4;

  {
    const int jd = tid;
    const float* src = (jd < kH) ? (Wih_fw + jd * kD) : (Wih_bw + (jd - kH) * kD);
    const float4* s4 = (const float4*)src;
#pragma unroll
    for (int k = 0; k < 8; ++k) {
      float4 a = s4[2 * k], c = s4[2 * k + 1];
      half8 h;
      h[0] = (_Float16)a.x; h[1] = (_Float16)a.y; h[2] = (_Float16)a.z; h[3] = (_Float16)a.w;
      h[4] = (_Float16)c.x; h[5] = (_Float16)c.y; h[6] = (_Float16)c.z; h[7] = (_Float16)c.w;
      *(half8*)&Wl[jd * 80 + k * 8] = h;
    }
    biasl[jd] = (jd < kH) ? (bih_fw[jd] + bhh_fw[jd])
                          : (bih_bw[jd - kH] + bhh_bw[jd - kH]);
  }

  for (int ch = 0; ch < 8; ++ch) {
    __syncthreads();
    {
      const int tl = tid >> 1, hf = tid & 1;
      const float4* s4 = (const float4*)(inputs +
          ((size_t)b * kS + ch * 128 + tl) * kD + hf * 32);
#pragma unroll
      for (int k = 0; k < 4; ++k) {
        float4 a = s4[2 * k], c = s4[2 * k + 1];
        half8 h;
        h[0] = (_Float16)a.x; h[1] = (_Float16)a.y; h[2] = (_Float16)a.z; h[3] = (_Float16)a.w;
        h[4] = (_Float16)c.x; h[5] = (_Float16)c.y; h[6] = (_Float16)c.z; h[7] = (_Float16)c.w;
        *(half8*)&xl[tl * 80 + hf * 32 + k * 8] = h;
      }
    }
    __syncthreads();

    half8 bf0[4], bf1[4];
    float bs[4];
#pragma unroll
    for (int nn = 0; nn < 4; ++nn) {
      const int jd = (w * 4 + nn) * 16 + n16;
      bf0[nn] = *(const half8*)&Wl[jd * 80 + q * 8];
      bf1[nn] = *(const half8*)&Wl[jd * 80 + q * 8 + 32];
      bs[nn] = biasl[jd];
    }

#pragma unroll 2
    for (int m = 0; m < 8; ++m) {
      const int trow = m * 16 + n16;
      const half8 a0 = *(const half8*)&xl[trow * 80 + q * 8];
      const half8 a1 = *(const half8*)&xl[trow * 80 + q * 8 + 32];
#pragma unroll
      for (int nn = 0; nn < 4; ++nn) {
        f32x4 acc = {0.f, 0.f, 0.f, 0.f};
        acc = __builtin_amdgcn_mfma_f32_16x16x32_f16(a0, bf0[nn], acc, 0, 0, 0);
        acc = __builtin_amdgcn_mfma_f32_16x16x32_f16(a1, bf1[nn], acc, 0, 0, 0);
        const int jd = (w * 4 + nn) * 16 + n16;
        const int dir = jd >> 7, j = jd & 127;
        const size_t slab = (size_t)(dir * 256 + b) * (kS * kH);
#pragma unroll
        for (int r = 0; r < 4; ++r) {
          const int t = ch * 128 + m * 16 + q * 4 + r;
          const int tt = dir ? (kS - 1 - t) : t;
          xp[slab + (size_t)(tt >> 5) * (32 * kH) + (tt & 31) * kH + j] =
              (_Float16)(acc[r] + bs[nn]);
        }
      }
    }
  }
}

// =====================  Phase B: wave-autonomous recurrence  =====================
// 512 blocks x 64 threads (ONE wave): dir = blockIdx>>8, b = blockIdx&255.
// Lane L finalizes j0=2L, j1=2L+1 with FULL K=128: no reduction, no barrier.
// h broadcast via ds_bpermute (uniform index): VGPR source -> VGPR dest, no
// SGPR hop (no v_mov fat), no LDS write->read RAW serialization. jrn ring is
// write-only in the step loop (fc journal, drained once per 32-step chunk).
// Dots issue on VALU while bpermutes stream on the LDS pipe.
__global__ __launch_bounds__(64, 1) void birnn_step_kernel(
    const _Float16* __restrict__ xp,
    const float* __restrict__ Whh_fw, const float* __restrict__ Whh_bw,
    const float* __restrict__ fcW, const float* __restrict__ fcb,
    float* __restrict__ out) {
  const int dir = blockIdx.x >> 8;
  const int b = blockIdx.x & 255;
  const int L = threadIdx.x;

  __shared__ unsigned jrn[32 * 68];   // fc journal, 68-dw rows (b128-aligned)
  __shared__ unsigned xbuf[2][2048];  // two 8 KB xp chunks
  __shared__ unsigned fcwl[64];       // fc weights, packed f16 pairs
  __shared__ float outbuf[kS];

  const float* __restrict__ Whh = dir ? Whh_bw : Whh_fw;

  // ---- weights: rows j0,j1 -> 128 packed-f16 dwords (w[k]=(W[j][2k],W[j][2k+1]))
  unsigned w0[64], w1[64];
  {
    const float* r0 = Whh + (size_t)(2 * L) * kH;
    const float* r1 = Whh + (size_t)(2 * L + 1) * kH;
#pragma unroll
    for (int k = 0; k < 64; ++k) {
      w0[k] = pk16(r0[2 * k], r0[2 * k + 1]);
      w1[k] = pk16(r1[2 * k], r1[2 * k + 1]);
    }
  }
  fcwl[L] = pk16(fcW[dir * kH + 2 * L], fcW[dir * kH + 2 * L + 1]);

  unsigned hcur = 0;  // h_{-1} = 0 (lane-local packed pair)

  // ---- prime xp chunks 0,1 ----
  const char* slab = (const char*)(xp + (size_t)(dir * 256 + b) * (kS * kH));
  stage_chunk(slab, &xbuf[0][0], L);
  stage_chunk(slab + 8192, &xbuf[1][0], L);
  asm volatile("s_waitcnt vmcnt(0)" ::: "memory");

  for (int c = 0; c < 32; ++c) {
    const unsigned* xb = &xbuf[c & 1][0];

#pragma unroll 2
    for (int s = 0; s < 32; ++s) {
      const unsigned xdw = xb[s * 64 + L];  // issue early; used after the dots
      float a0 = 0.f, a1 = 0.f, a2 = 0.f, a3 = 0.f;
      float c0 = 0.f, c1 = 0.f, c2 = 0.f, c3 = 0.f;

      unsigned hb[32];
      // ---- half 0: broadcast k=0..31 via bpermute, then 64 dots ----
#pragma unroll
      for (int k = 0; k < 32; ++k) hb[k] = bcast(hcur, k);
#pragma unroll
      for (int k = 0; k < 32; ++k) {
        a0 = fdot2(w0[k], hb[k], a0);
        c0 = fdot2(w1[k], hb[k], c0);
        // rotate accumulator names via index math on the unrolled k:
        // handled below by separate chains — see half 1 comment
      }
      // ---- half 1: broadcast k=32..63, then 64 dots on the other chains ----
#pragma unroll
      for (int k = 0; k < 32; ++k) hb[k] = bcast(hcur, 32 + k);
#pragma unroll
      for (int k = 0; k < 32; ++k) {
        a1 = fdot2(w0[32 + k], hb[k], a1);
        c1 = fdot2(w1[32 + k], hb[k], c1);
      }
      (void)a2; (void)a3; (void)c2; (void)c3;

      const half2v xh = __builtin_bit_cast(half2v, xdw);
      const float va = (a0 + a1) + (float)xh.x;
      const float vb = (c0 + c1) + (float)xh.y;
      hcur = pk16(fast_tanh(va), fast_tanh(vb));
      jrn[s * 68 + L] = hcur;  // journal only; not read until fc drain
    }

    // ---- fc drain of chunk c ----
    {
      const int tl = L >> 1, jh = L & 1;
      const uint4* rp = (const uint4*)&jrn[tl * 68 + jh * 32];
      const uint4* fp = (const uint4*)&fcwl[jh * 32];
      float acc = 0.f;
#pragma unroll
      for (int k = 0; k < 8; ++k) {
        const uint4 hv = rp[k];
        const uint4 fw = fp[k];
        acc = fdot2(fw.x, hv.x, acc);
        acc = fdot2(fw.y, hv.y, acc);
        acc = fdot2(fw.z, hv.z, acc);
        acc = fdot2(fw.w, hv.w, acc);
      }
      acc += lane_xor1(acc);
      if (jh == 0) outbuf[c * 32 + tl] = acc;
    }

    // ---- stage chunk c+2 into the buffer just freed; gate chunk c+1 ----
    if (c < 30) {
      stage_chunk(slab + (size_t)(c + 2) * 8192, &xbuf[c & 1][0], L);
      asm volatile("s_waitcnt vmcnt(8)" ::: "memory");
    } else if (c == 30) {
      asm volatile("s_waitcnt vmcnt(0)" ::: "memory");
    }
  }

  // ---- emit: one atomic pass (fw adds fcb) ----
  const float fcb0 = (dir == 0) ? fcb[0] : 0.f;
#pragma unroll
  for (int k = 0; k < 16; ++k) {
    const int t = L + 64 * k;
    const int td = dir ? (kS - 1 - t) : t;
    atomicAdd(&out[(size_t)b * kS + td], outbuf[t] + fcb0);
  }
}

}  // namespace

extern "C" void kernel_launch(void* const* d_in, const int* in_sizes, int n_in,
                              void* d_out, int out_size, void* d_ws, size_t ws_size,
                              hipStream_t stream) {
  (void)in_sizes; (void)n_in; (void)ws_size;
  const float* inputs = (const float*)d_in[0];
  const float* Wih_fw = (const float*)d_in[1];
  const float* Whh_fw = (const float*)d_in[2];
  const float* bih_fw = (const float*)d_in[3];
  const float* bhh_fw = (const float*)d_in[4];
  const float* Wih_bw = (const float*)d_in[5];
  const float* Whh_bw = (const float*)d_in[6];
  const float* bih_bw = (const float*)d_in[7];
  const float* bhh_bw = (const float*)d_in[8];
  const float* fc_W   = (const float*)d_in[9];
  const float* fc_b   = (const float*)d_in[10];
  float* out = (float*)d_out;
  _Float16* xpw = (_Float16*)d_ws;  // 2*256*1024*128 f16 = 128 MiB

  hipMemsetAsync(out, 0, (size_t)out_size * sizeof(float), stream);

  hipLaunchKernelGGL(xproj_kernel, dim3(256), dim3(256), 0, stream,
                     inputs, Wih_fw, bih_fw, bhh_fw, Wih_bw, bih_bw, bhh_bw, xpw);
  hipLaunchKernelGGL(birnn_step_kernel, dim3(512), dim3(64), 0, stream,
                     xpw, Whh_fw, Whh_bw, fc_W, fc_b, out);
}